// Round 7
// baseline (360.077 us; speedup 1.0000x reference)
//
#include <hip/hip_runtime.h>

typedef __attribute__((ext_vector_type(8))) short bf16x8;
typedef __attribute__((ext_vector_type(4))) short bf16x4;
typedef __attribute__((ext_vector_type(4))) float f32x4;
typedef __attribute__((ext_vector_type(4))) float floatx4;

__device__ __forceinline__ unsigned short f2bf(float f) {
    unsigned int u = __float_as_uint(f);
    u += 0x7fffu + ((u >> 16) & 1u);   // round-to-nearest-even
    return (unsigned short)(u >> 16);
}
__device__ __forceinline__ float bf2f_s(short h) {
    return __uint_as_float(((unsigned int)(unsigned short)h) << 16);
}

// pack 8 f32 -> bf16x8 via HW packed convert (RNE)
__device__ __forceinline__ bf16x8 cvt8(f32x4 lo, f32x4 hi) {
    union { unsigned int u[4]; bf16x8 v; } r;
    asm("v_cvt_pk_bf16_f32 %0, %1, %2" : "=v"(r.u[0]) : "v"(lo[0]), "v"(lo[1]));
    asm("v_cvt_pk_bf16_f32 %0, %1, %2" : "=v"(r.u[1]) : "v"(lo[2]), "v"(lo[3]));
    asm("v_cvt_pk_bf16_f32 %0, %1, %2" : "=v"(r.u[2]) : "v"(hi[0]), "v"(hi[1]));
    asm("v_cvt_pk_bf16_f32 %0, %1, %2" : "=v"(r.u[3]) : "v"(hi[2]), "v"(hi[3]));
    return r.v;
}

// ---------------- kernel 0: Wo -> bf16 (only weight k3 needs from ws) ----------------
__global__ void k_convert(const float* __restrict__ Wo, unsigned short* __restrict__ Wob) {
    int i = (blockIdx.x * blockDim.x + threadIdx.x) * 4;
    if (i < 131072) {
        floatx4 c = *reinterpret_cast<const floatx4*>(Wo + i);
        bf16x4 sc;
        #pragma unroll
        for (int e = 0; e < 4; ++e) sc[e] = (short)f2bf(c[e]);
        *reinterpret_cast<bf16x4*>(Wob + i) = sc;
    }
}

// ---------------- kernel 1: keys/vals GEMM (register-direct, inputs only from d_in) ----------------
// kv[m][n] = sum_e patches[m][e] * bf16(W[n][e])  (+ patch_pos bias for n<128)
// W rows: n<128 -> Wk[n], n>=128 -> Wv[n-128]. Block = 64M x 256N, 4 waves;
// wave = 64M x 64N tile, acc[4][4]. A and B both f32 direct loads -> cvt_pk bf16.
// No LDS, no barriers, no cross-kernel ws dependency. Fully unrolled BK=32 steps.
__global__ __launch_bounds__(256, 2)
void k_keysvals(const float* __restrict__ patches,
                const float* __restrict__ Wk,
                const float* __restrict__ Wv,
                const float* __restrict__ patch_pos,
                unsigned short* __restrict__ kv)
{
    const int tid  = threadIdx.x;
    const int lane = tid & 63;
    const int wn   = tid >> 6;        // wave index = N-quarter (0..3)
    const int l15  = lane & 15;
    const int lg   = lane >> 4;       // 0..3
    const int row0 = blockIdx.x * 64;

    // A fragment bases: rows row0 + {0,16,32,48} + l15, k-chunk lg*8
    const float* ap0 = patches + (size_t)(row0 +  0 + l15) * 1024 + lg * 8;
    const float* ap1 = patches + (size_t)(row0 + 16 + l15) * 1024 + lg * 8;
    const float* ap2 = patches + (size_t)(row0 + 32 + l15) * 1024 + lg * 8;
    const float* ap3 = patches + (size_t)(row0 + 48 + l15) * 1024 + lg * 8;

    // B fragment bases: waves 0/1 -> Wk rows 0-127, waves 2/3 -> Wv rows 0-127
    const float* wsrc = (wn < 2) ? Wk : Wv;
    const int    nloc = (wn & 1) * 64;
    const float* bp0 = wsrc + (size_t)(nloc +  0 + l15) * 1024 + lg * 8;
    const float* bp1 = wsrc + (size_t)(nloc + 16 + l15) * 1024 + lg * 8;
    const float* bp2 = wsrc + (size_t)(nloc + 32 + l15) * 1024 + lg * 8;
    const float* bp3 = wsrc + (size_t)(nloc + 48 + l15) * 1024 + lg * 8;

    f32x4 acc[4][4];
    #pragma unroll
    for (int i = 0; i < 4; ++i)
        #pragma unroll
        for (int j = 0; j < 4; ++j)
            acc[i][j] = (f32x4){0.f, 0.f, 0.f, 0.f};

    #pragma unroll
    for (int t = 0; t < 32; ++t) {
        const int o = t * 32;   // floats per BK step
        bf16x8 af[4], bfr[4];
        af[0] = cvt8(*reinterpret_cast<const f32x4*>(ap0 + o),
                     *reinterpret_cast<const f32x4*>(ap0 + o + 4));
        af[1] = cvt8(*reinterpret_cast<const f32x4*>(ap1 + o),
                     *reinterpret_cast<const f32x4*>(ap1 + o + 4));
        af[2] = cvt8(*reinterpret_cast<const f32x4*>(ap2 + o),
                     *reinterpret_cast<const f32x4*>(ap2 + o + 4));
        af[3] = cvt8(*reinterpret_cast<const f32x4*>(ap3 + o),
                     *reinterpret_cast<const f32x4*>(ap3 + o + 4));
        bfr[0] = cvt8(*reinterpret_cast<const f32x4*>(bp0 + o),
                      *reinterpret_cast<const f32x4*>(bp0 + o + 4));
        bfr[1] = cvt8(*reinterpret_cast<const f32x4*>(bp1 + o),
                      *reinterpret_cast<const f32x4*>(bp1 + o + 4));
        bfr[2] = cvt8(*reinterpret_cast<const f32x4*>(bp2 + o),
                      *reinterpret_cast<const f32x4*>(bp2 + o + 4));
        bfr[3] = cvt8(*reinterpret_cast<const f32x4*>(bp3 + o),
                      *reinterpret_cast<const f32x4*>(bp3 + o + 4));
        #pragma unroll
        for (int mi = 0; mi < 4; ++mi)
            #pragma unroll
            for (int ni = 0; ni < 4; ++ni)
                acc[mi][ni] = __builtin_amdgcn_mfma_f32_16x16x32_bf16(af[mi], bfr[ni], acc[mi][ni], 0, 0, 0);
    }

    // epilogue: C/D layout col=lane&15 (n), row=(lane>>4)*4+i (m)
    #pragma unroll
    for (int mi = 0; mi < 4; ++mi) {
        #pragma unroll
        for (int i = 0; i < 4; ++i) {
            int m  = row0 + mi * 16 + lg * 4 + i;
            int kp = m % 196;
            #pragma unroll
            for (int ni = 0; ni < 4; ++ni) {
                int n = wn * 64 + ni * 16 + l15;
                float v = acc[mi][ni][i];
                if (wn < 2) v += patch_pos[kp * 128 + n];   // n<128 <=> wn<2
                kv[(size_t)m * 256 + n] = f2bf(v);
            }
        }
    }
}

// ---------------- kernel 2: per-batch attention ----------------
__global__ __launch_bounds__(1024)
void k_attn(const unsigned short* __restrict__ kv,
            const float* __restrict__ queries,
            const float* __restrict__ prior,
            const float* __restrict__ temperature,
            float* __restrict__ attn_out,
            unsigned short* __restrict__ att)
{
    __shared__ unsigned short k_s[196][136];
    __shared__ unsigned short v_s[196][128];
    __shared__ unsigned short q_s[52][128];
    __shared__ float          l_s[52][196];

    const int b   = blockIdx.x;
    const int tid = threadIdx.x;
    const size_t base = (size_t)b * 196 * 256;

    for (int idx = tid; idx < 6272; idx += 1024) {
        int row = idx >> 5;
        int c   = (idx & 31) * 8;
        bf16x8 v = *reinterpret_cast<const bf16x8*>(kv + base + row * 256 + c);
        if (c < 128) *reinterpret_cast<bf16x8*>(&k_s[row][c])       = v;
        else         *reinterpret_cast<bf16x8*>(&v_s[row][c - 128]) = v;
    }
    for (int idx = tid; idx < 1664; idx += 1024) {
        int row = idx >> 5;
        int c   = (idx & 31) * 4;
        const float* qp = queries + row * 128 + c;
        bf16x4 sv;
        sv[0] = (short)f2bf(qp[0]); sv[1] = (short)f2bf(qp[1]);
        sv[2] = (short)f2bf(qp[2]); sv[3] = (short)f2bf(qp[3]);
        *reinterpret_cast<bf16x4*>(&q_s[row][c]) = sv;
    }
    __syncthreads();

    const float inv_temp  = 1.0f / (log1pf(expf(temperature[0])) + 0.5f);
    const float inv_scale = 0.08838834764831845f;

    for (int task = tid; task < 3328; task += 1024) {
        int q  = task >> 6;
        int kg = task & 63;
        if (kg < 49) {
            float dot0 = 0.f, dot1 = 0.f, dot2 = 0.f, dot3 = 0.f;
            #pragma unroll 4
            for (int c = 0; c < 128; c += 8) {
                bf16x8 qv = *reinterpret_cast<const bf16x8*>(&q_s[q][c]);
                float qf[8];
                #pragma unroll
                for (int e = 0; e < 8; ++e) qf[e] = bf2f_s(qv[e]);
                bf16x8 k0v = *reinterpret_cast<const bf16x8*>(&k_s[kg][c]);
                bf16x8 k1v = *reinterpret_cast<const bf16x8*>(&k_s[kg + 49][c]);
                bf16x8 k2v = *reinterpret_cast<const bf16x8*>(&k_s[kg + 98][c]);
                bf16x8 k3v = *reinterpret_cast<const bf16x8*>(&k_s[kg + 147][c]);
                #pragma unroll
                for (int e = 0; e < 8; ++e) {
                    dot0 += qf[e] * bf2f_s(k0v[e]);
                    dot1 += qf[e] * bf2f_s(k1v[e]);
                    dot2 += qf[e] * bf2f_s(k2v[e]);
                    dot3 += qf[e] * bf2f_s(k3v[e]);
                }
            }
            int k;
            k = kg;       l_s[q][k] = (dot0 * inv_scale + prior[q * 196 + k]) * inv_temp;
            k = kg + 49;  l_s[q][k] = (dot1 * inv_scale + prior[q * 196 + k]) * inv_temp;
            k = kg + 98;  l_s[q][k] = (dot2 * inv_scale + prior[q * 196 + k]) * inv_temp;
            k = kg + 147; l_s[q][k] = (dot3 * inv_scale + prior[q * 196 + k]) * inv_temp;
        }
    }
    __syncthreads();

    const int lane = tid & 63;
    const int wave = tid >> 6;
    for (int q = wave; q < 52; q += 16) {
        float x0 = l_s[q][lane];
        float x1 = l_s[q][lane + 64];
        float x2 = l_s[q][lane + 128];
        float x3 = (lane < 4) ? l_s[q][lane + 192] : -1e30f;
        float m = fmaxf(fmaxf(x0, x1), fmaxf(x2, x3));
        #pragma unroll
        for (int off = 32; off > 0; off >>= 1) m = fmaxf(m, __shfl_xor(m, off));
        float e0 = expf(x0 - m), e1 = expf(x1 - m), e2 = expf(x2 - m);
        float e3 = (lane < 4) ? expf(x3 - m) : 0.0f;
        float s = e0 + e1 + e2 + e3;
        #pragma unroll
        for (int off = 32; off > 0; off >>= 1) s += __shfl_xor(s, off);
        float inv = 1.0f / s;
        float* po = attn_out + ((size_t)b * 52 + q) * 196;
        float a0 = e0 * inv, a1 = e1 * inv, a2 = e2 * inv;
        l_s[q][lane]       = a0;  po[lane]       = a0;
        l_s[q][lane + 64]  = a1;  po[lane + 64]  = a1;
        l_s[q][lane + 128] = a2;  po[lane + 128] = a2;
        if (lane < 4) { float a3 = e3 * inv; l_s[q][lane + 192] = a3; po[lane + 192] = a3; }
    }
    __syncthreads();

    if (tid < 832) {
        int q  = tid >> 4;
        int a0 = (tid & 15) * 8;
        float accv[8] = {0.f, 0.f, 0.f, 0.f, 0.f, 0.f, 0.f, 0.f};
        for (int k = 0; k < 196; ++k) {
            float w = l_s[q][k];
            bf16x8 vv = *reinterpret_cast<const bf16x8*>(&v_s[k][a0]);
            #pragma unroll
            for (int e = 0; e < 8; ++e) accv[e] += w * bf2f_s(vv[e]);
        }
        bf16x8 sv;
        #pragma unroll
        for (int e = 0; e < 8; ++e) sv[e] = (short)f2bf(accv[e]);
        *reinterpret_cast<bf16x8*>(att + ((size_t)b * 52 + q) * 128 + a0) = sv;
    }
}

// ---------------- kernel 3: output GEMM ----------------
__global__ __launch_bounds__(512)
void k_out(const unsigned short* __restrict__ att,
           const unsigned short* __restrict__ Wob,
           const float* __restrict__ bo,
           float* __restrict__ out)
{
    __shared__ unsigned short As[64][72];
    __shared__ unsigned short Bs[256][72];

    const int tid  = threadIdx.x;
    const int lane = tid & 63;
    const int wave = tid >> 6;
    const int wm   = wave >> 2;
    const int wn   = wave & 3;
    const int l15  = lane & 15;
    const int lg   = lane >> 4;
    const int row0 = blockIdx.x * 64;
    const int e0   = blockIdx.y * 256;

    f32x4 acc[2][4];
    #pragma unroll
    for (int i = 0; i < 2; ++i)
        #pragma unroll
        for (int j = 0; j < 4; ++j)
            acc[i][j] = (f32x4){0.f, 0.f, 0.f, 0.f};

    for (int ko = 0; ko < 128; ko += 64) {
        {
            int r = tid >> 3;
            int c = (tid & 7) * 8;
            bf16x8 v = *reinterpret_cast<const bf16x8*>(att + (size_t)(row0 + r) * 128 + ko + c);
            *reinterpret_cast<bf16x8*>(&As[r][c]) = v;
        }
        {
            int r = tid >> 3;
            int c = (tid & 7) * 8;
            #pragma unroll
            for (int it = 0; it < 4; ++it) {
                bf16x8 v = *reinterpret_cast<const bf16x8*>(Wob + (size_t)(e0 + it * 64 + r) * 128 + ko + c);
                *reinterpret_cast<bf16x8*>(&Bs[it * 64 + r][c]) = v;
            }
        }
        __syncthreads();
        #pragma unroll
        for (int kk = 0; kk < 2; ++kk) {
            bf16x8 af[2], bfr[4];
            #pragma unroll
            for (int mi = 0; mi < 2; ++mi)
                af[mi] = *reinterpret_cast<const bf16x8*>(&As[wm * 32 + mi * 16 + l15][kk * 32 + lg * 8]);
            #pragma unroll
            for (int ni = 0; ni < 4; ++ni)
                bfr[ni] = *reinterpret_cast<const bf16x8*>(&Bs[wn * 64 + ni * 16 + l15][kk * 32 + lg * 8]);
            #pragma unroll
            for (int mi = 0; mi < 2; ++mi)
                #pragma unroll
                for (int ni = 0; ni < 4; ++ni)
                    acc[mi][ni] = __builtin_amdgcn_mfma_f32_16x16x32_bf16(af[mi], bfr[ni], acc[mi][ni], 0, 0, 0);
        }
        __syncthreads();
    }
    #pragma unroll
    for (int mi = 0; mi < 2; ++mi) {
        #pragma unroll
        for (int i = 0; i < 4; ++i) {
            int m = row0 + wm * 32 + mi * 16 + lg * 4 + i;
            #pragma unroll
            for (int ni = 0; ni < 4; ++ni) {
                int e = e0 + wn * 64 + ni * 16 + l15;
                out[(size_t)m * 1024 + e] = acc[mi][ni][i] + bo[e];
            }
        }
    }
}

extern "C" void kernel_launch(void* const* d_in, const int* in_sizes, int n_in,
                              void* d_out, int out_size, void* d_ws, size_t ws_size,
                              hipStream_t stream)
{
    const float* patches     = (const float*)d_in[0];   // [256][196][1024]
    const float* queries     = (const float*)d_in[1];   // [52][128]
    const float* Wk          = (const float*)d_in[2];   // [128][1024]
    const float* Wv          = (const float*)d_in[3];   // [128][1024]
    const float* Wo          = (const float*)d_in[4];   // [1024][128]
    const float* bo          = (const float*)d_in[5];   // [1024]
    const float* patch_pos   = (const float*)d_in[6];   // [196][128]
    const float* temperature = (const float*)d_in[7];   // [1]
    const float* prior       = (const float*)d_in[8];   // [52][196]

    float* out      = (float*)d_out;                    // [256*52][1024]
    float* attn_out = out + (size_t)256 * 52 * 1024;    // [256*52][196]

    unsigned short* Wob = (unsigned short*)d_ws;               // 1024*128
    unsigned short* kv  = Wob + 1024 * 128;                    // 50176*256
    unsigned short* att = kv + (size_t)50176 * 256;            // 13312*128

    k_convert <<<128, 256, 0, stream>>>(Wo, Wob);
    k_keysvals<<<784, 256, 0, stream>>>(patches, Wk, Wv, patch_pos, kv);
    k_attn    <<<256, 1024, 0, stream>>>(kv, queries, prior, temperature, attn_out, att);
    k_out     <<<dim3(208, 4), 512, 0, stream>>>(att, Wob, bo, out);
}

// Round 8
// 197.102 us; speedup vs baseline: 1.8269x; 1.8269x over previous
//
#include <hip/hip_runtime.h>

typedef __attribute__((ext_vector_type(8))) short bf16x8;
typedef __attribute__((ext_vector_type(4))) short bf16x4;
typedef __attribute__((ext_vector_type(4))) float f32x4;
typedef __attribute__((ext_vector_type(4))) float floatx4;

__device__ __forceinline__ unsigned short f2bf(float f) {
    unsigned int u = __float_as_uint(f);
    u += 0x7fffu + ((u >> 16) & 1u);   // round-to-nearest-even
    return (unsigned short)(u >> 16);
}
__device__ __forceinline__ float bf2f_s(short h) {
    return __uint_as_float(((unsigned int)(unsigned short)h) << 16);
}

// pack 8 f32 -> bf16x8 via HW packed convert (RNE)
__device__ __forceinline__ bf16x8 cvt8(f32x4 lo, f32x4 hi) {
    union { unsigned int u[4]; bf16x8 v; } r;
    asm("v_cvt_pk_bf16_f32 %0, %1, %2" : "=v"(r.u[0]) : "v"(lo[0]), "v"(lo[1]));
    asm("v_cvt_pk_bf16_f32 %0, %1, %2" : "=v"(r.u[1]) : "v"(lo[2]), "v"(lo[3]));
    asm("v_cvt_pk_bf16_f32 %0, %1, %2" : "=v"(r.u[2]) : "v"(hi[0]), "v"(hi[1]));
    asm("v_cvt_pk_bf16_f32 %0, %1, %2" : "=v"(r.u[3]) : "v"(hi[2]), "v"(hi[3]));
    return r.v;
}

// ---------------- kernel 0: Wo -> bf16 (only k3 consumes ws weights) ----------------
__global__ void k_convert(const float* __restrict__ Wo, unsigned short* __restrict__ Wob) {
    int i = (blockIdx.x * blockDim.x + threadIdx.x) * 4;
    if (i < 131072) {
        floatx4 c = *reinterpret_cast<const floatx4*>(Wo + i);
        bf16x4 sc;
        #pragma unroll
        for (int e = 0; e < 4; ++e) sc[e] = (short)f2bf(c[e]);
        *reinterpret_cast<bf16x4*>(Wob + i) = sc;
    }
}

// ---------------- kernel 1: keys/vals GEMM (reg-staged, counted-vmcnt dbuf) ----------------
// kv[m][n] = sum_e patches[m][e] * bf16(W[n][e])  (+ patch_pos for n<128)
// BM=128 (grid 392, A rows exclusive -> A read once), BN=256 (full N), BK=32.
// 512 thr, 8 waves (2M x 4N), wave tile 64x64, acc[4][4].
// Staging: plain global loads -> regs -> cvt_pk -> ds_write (no global_load_lds).
// Barrier = raw s_barrier with ONLY lgkmcnt(0) flushed; vmcnt never drained ->
// next-next tile's loads stay in flight across barriers (compiler-counted waits).
__global__ __launch_bounds__(512, 4)
void k_keysvals(const float* __restrict__ patches,
                const float* __restrict__ Wk,
                const float* __restrict__ Wv,
                const float* __restrict__ patch_pos,
                unsigned short* __restrict__ kv)
{
    // per buffer: A 128 rows x 80B (10240B) | B 256 rows x 80B (20480B); stride 80
    // = 20 words -> row bank-base pattern period 8, 2-way max on b128 ops (free).
    __shared__ char ldsb[2][30720];

    const int tid  = threadIdx.x;
    const int lane = tid & 63;
    const int wave = tid >> 6;       // 0..7
    const int wm   = wave >> 2;      // 0..1 : 64-row half
    const int wn   = wave & 3;       // 0..3 : 64-col quarter
    const int l15  = lane & 15;
    const int lg   = lane >> 4;      // 0..3
    const int row0 = blockIdx.x * 128;

    // A staging task: thread -> (row arow, granule a4) ; 32B = 8 f32 per thread/step
    const int arow = tid >> 2;               // 0..127
    const int a4   = tid & 3;                // granule 0..3 (k = a4*8..a4*8+7)
    const float* agp = patches + (size_t)(row0 + arow) * 1024 + a4 * 8;

    // B staging task: thread -> (row brow, k-half bh) ; 64B = 16 f32 per thread/step
    const int brow = tid >> 1;               // 0..255  (waves 0-3 -> Wk, 4-7 -> Wv)
    const int bh   = tid & 1;                // k-half (granules 2bh, 2bh+1)
    const float* bgp = ((wave < 4) ? (Wk + (size_t)brow * 1024)
                                   : (Wv + (size_t)(brow - 128) * 1024)) + bh * 16;

    f32x4 R0, R1, R2, R3, R4, R5;            // staged tile in regs (one K-step)

    f32x4 acc[4][4];
    #pragma unroll
    for (int i = 0; i < 4; ++i)
        #pragma unroll
        for (int j = 0; j < 4; ++j)
            acc[i][j] = (f32x4){0.f, 0.f, 0.f, 0.f};

    auto issue = [&](int s) {
        const int ko = s * 32;
        R0 = *reinterpret_cast<const f32x4*>(agp + ko);
        R1 = *reinterpret_cast<const f32x4*>(agp + ko + 4);
        R2 = *reinterpret_cast<const f32x4*>(bgp + ko);
        R3 = *reinterpret_cast<const f32x4*>(bgp + ko + 4);
        R4 = *reinterpret_cast<const f32x4*>(bgp + ko + 8);
        R5 = *reinterpret_cast<const f32x4*>(bgp + ko + 12);
    };
    auto store = [&](char* buf) {
        *reinterpret_cast<bf16x8*>(buf + arow * 80 + a4 * 16) = cvt8(R0, R1);
        char* bb = buf + 10240 + brow * 80 + bh * 32;
        *reinterpret_cast<bf16x8*>(bb)      = cvt8(R2, R3);
        *reinterpret_cast<bf16x8*>(bb + 16) = cvt8(R4, R5);
    };
    auto compute = [&](const char* buf) {
        bf16x8 af[4], bf[4];
        #pragma unroll
        for (int mf = 0; mf < 4; ++mf)
            af[mf] = *reinterpret_cast<const bf16x8*>(buf + (wm * 64 + mf * 16 + l15) * 80 + lg * 16);
        #pragma unroll
        for (int nf = 0; nf < 4; ++nf)
            bf[nf] = *reinterpret_cast<const bf16x8*>(buf + 10240 + (wn * 64 + nf * 16 + l15) * 80 + lg * 16);
        #pragma unroll
        for (int mf = 0; mf < 4; ++mf)
            #pragma unroll
            for (int nf = 0; nf < 4; ++nf)
                acc[mf][nf] = __builtin_amdgcn_mfma_f32_16x16x32_bf16(af[mf], bf[nf], acc[mf][nf], 0, 0, 0);
    };

    // prologue: tile0 -> buf0; tile1 loads in flight
    issue(0);
    store(ldsb[0]);          // compiler inserts counted vmcnt for R-use
    issue(1);
    __builtin_amdgcn_sched_barrier(0);
    asm volatile("s_waitcnt lgkmcnt(0)" ::: "memory");
    __builtin_amdgcn_s_barrier();
    __builtin_amdgcn_sched_barrier(0);

    for (int t = 0; t < 32; ++t) {
        compute(ldsb[t & 1]);                 // no dependency on in-flight loads
        if (t < 31) store(ldsb[(t + 1) & 1]); // writes tile t+1 (R); vmcnt auto-counted
        if (t < 30) issue(t + 2);             // stays in flight across the barrier
        __builtin_amdgcn_sched_barrier(0);
        asm volatile("s_waitcnt lgkmcnt(0)" ::: "memory");   // flush LDS ops only
        __builtin_amdgcn_s_barrier();                         // vmcnt NOT drained
        __builtin_amdgcn_sched_barrier(0);
    }

    // epilogue: C/D layout col=lane&15 (n), row=(lane>>4)*4+i (m)
    #pragma unroll
    for (int mf = 0; mf < 4; ++mf) {
        #pragma unroll
        for (int i = 0; i < 4; ++i) {
            int m  = row0 + wm * 64 + mf * 16 + lg * 4 + i;
            int kp = m % 196;
            #pragma unroll
            for (int nf = 0; nf < 4; ++nf) {
                int n = wn * 64 + nf * 16 + l15;
                float v = acc[mf][nf][i];
                if (wn < 2) v += patch_pos[kp * 128 + n];    // n<128 <=> wn<2
                kv[(size_t)m * 256 + n] = f2bf(v);
            }
        }
    }
}

// ---------------- kernel 2: per-batch attention ----------------
__global__ __launch_bounds__(1024)
void k_attn(const unsigned short* __restrict__ kv,
            const float* __restrict__ queries,
            const float* __restrict__ prior,
            const float* __restrict__ temperature,
            float* __restrict__ attn_out,
            unsigned short* __restrict__ att)
{
    __shared__ unsigned short k_s[196][136];
    __shared__ unsigned short v_s[196][128];
    __shared__ unsigned short q_s[52][128];
    __shared__ float          l_s[52][196];

    const int b   = blockIdx.x;
    const int tid = threadIdx.x;
    const size_t base = (size_t)b * 196 * 256;

    for (int idx = tid; idx < 6272; idx += 1024) {
        int row = idx >> 5;
        int c   = (idx & 31) * 8;
        bf16x8 v = *reinterpret_cast<const bf16x8*>(kv + base + row * 256 + c);
        if (c < 128) *reinterpret_cast<bf16x8*>(&k_s[row][c])       = v;
        else         *reinterpret_cast<bf16x8*>(&v_s[row][c - 128]) = v;
    }
    for (int idx = tid; idx < 1664; idx += 1024) {
        int row = idx >> 5;
        int c   = (idx & 31) * 4;
        const float* qp = queries + row * 128 + c;
        bf16x4 sv;
        sv[0] = (short)f2bf(qp[0]); sv[1] = (short)f2bf(qp[1]);
        sv[2] = (short)f2bf(qp[2]); sv[3] = (short)f2bf(qp[3]);
        *reinterpret_cast<bf16x4*>(&q_s[row][c]) = sv;
    }
    __syncthreads();

    const float inv_temp  = 1.0f / (log1pf(expf(temperature[0])) + 0.5f);
    const float inv_scale = 0.08838834764831845f;

    for (int task = tid; task < 3328; task += 1024) {
        int q  = task >> 6;
        int kg = task & 63;
        if (kg < 49) {
            float dot0 = 0.f, dot1 = 0.f, dot2 = 0.f, dot3 = 0.f;
            #pragma unroll 4
            for (int c = 0; c < 128; c += 8) {
                bf16x8 qv = *reinterpret_cast<const bf16x8*>(&q_s[q][c]);
                float qf[8];
                #pragma unroll
                for (int e = 0; e < 8; ++e) qf[e] = bf2f_s(qv[e]);
                bf16x8 k0v = *reinterpret_cast<const bf16x8*>(&k_s[kg][c]);
                bf16x8 k1v = *reinterpret_cast<const bf16x8*>(&k_s[kg + 49][c]);
                bf16x8 k2v = *reinterpret_cast<const bf16x8*>(&k_s[kg + 98][c]);
                bf16x8 k3v = *reinterpret_cast<const bf16x8*>(&k_s[kg + 147][c]);
                #pragma unroll
                for (int e = 0; e < 8; ++e) {
                    dot0 += qf[e] * bf2f_s(k0v[e]);
                    dot1 += qf[e] * bf2f_s(k1v[e]);
                    dot2 += qf[e] * bf2f_s(k2v[e]);
                    dot3 += qf[e] * bf2f_s(k3v[e]);
                }
            }
            int k;
            k = kg;       l_s[q][k] = (dot0 * inv_scale + prior[q * 196 + k]) * inv_temp;
            k = kg + 49;  l_s[q][k] = (dot1 * inv_scale + prior[q * 196 + k]) * inv_temp;
            k = kg + 98;  l_s[q][k] = (dot2 * inv_scale + prior[q * 196 + k]) * inv_temp;
            k = kg + 147; l_s[q][k] = (dot3 * inv_scale + prior[q * 196 + k]) * inv_temp;
        }
    }
    __syncthreads();

    const int lane = tid & 63;
    const int wave = tid >> 6;
    for (int q = wave; q < 52; q += 16) {
        float x0 = l_s[q][lane];
        float x1 = l_s[q][lane + 64];
        float x2 = l_s[q][lane + 128];
        float x3 = (lane < 4) ? l_s[q][lane + 192] : -1e30f;
        float m = fmaxf(fmaxf(x0, x1), fmaxf(x2, x3));
        #pragma unroll
        for (int off = 32; off > 0; off >>= 1) m = fmaxf(m, __shfl_xor(m, off));
        float e0 = expf(x0 - m), e1 = expf(x1 - m), e2 = expf(x2 - m);
        float e3 = (lane < 4) ? expf(x3 - m) : 0.0f;
        float s = e0 + e1 + e2 + e3;
        #pragma unroll
        for (int off = 32; off > 0; off >>= 1) s += __shfl_xor(s, off);
        float inv = 1.0f / s;
        float* po = attn_out + ((size_t)b * 52 + q) * 196;
        float a0 = e0 * inv, a1 = e1 * inv, a2 = e2 * inv;
        l_s[q][lane]       = a0;  po[lane]       = a0;
        l_s[q][lane + 64]  = a1;  po[lane + 64]  = a1;
        l_s[q][lane + 128] = a2;  po[lane + 128] = a2;
        if (lane < 4) { float a3 = e3 * inv; l_s[q][lane + 192] = a3; po[lane + 192] = a3; }
    }
    __syncthreads();

    if (tid < 832) {
        int q  = tid >> 4;
        int a0 = (tid & 15) * 8;
        float accv[8] = {0.f, 0.f, 0.f, 0.f, 0.f, 0.f, 0.f, 0.f};
        for (int k = 0; k < 196; ++k) {
            float w = l_s[q][k];
            bf16x8 vv = *reinterpret_cast<const bf16x8*>(&v_s[k][a0]);
            #pragma unroll
            for (int e = 0; e < 8; ++e) accv[e] += w * bf2f_s(vv[e]);
        }
        bf16x8 sv;
        #pragma unroll
        for (int e = 0; e < 8; ++e) sv[e] = (short)f2bf(accv[e]);
        *reinterpret_cast<bf16x8*>(att + ((size_t)b * 52 + q) * 128 + a0) = sv;
    }
}

// ---------------- kernel 3: output GEMM ----------------
__global__ __launch_bounds__(512)
void k_out(const unsigned short* __restrict__ att,
           const unsigned short* __restrict__ Wob,
           const float* __restrict__ bo,
           float* __restrict__ out)
{
    __shared__ unsigned short As[64][72];
    __shared__ unsigned short Bs[256][72];

    const int tid  = threadIdx.x;
    const int lane = tid & 63;
    const int wave = tid >> 6;
    const int wm   = wave >> 2;
    const int wn   = wave & 3;
    const int l15  = lane & 15;
    const int lg   = lane >> 4;
    const int row0 = blockIdx.x * 64;
    const int e0   = blockIdx.y * 256;

    f32x4 acc[2][4];
    #pragma unroll
    for (int i = 0; i < 2; ++i)
        #pragma unroll
        for (int j = 0; j < 4; ++j)
            acc[i][j] = (f32x4){0.f, 0.f, 0.f, 0.f};

    for (int ko = 0; ko < 128; ko += 64) {
        {
            int r = tid >> 3;
            int c = (tid & 7) * 8;
            bf16x8 v = *reinterpret_cast<const bf16x8*>(att + (size_t)(row0 + r) * 128 + ko + c);
            *reinterpret_cast<bf16x8*>(&As[r][c]) = v;
        }
        {
            int r = tid >> 3;
            int c = (tid & 7) * 8;
            #pragma unroll
            for (int it = 0; it < 4; ++it) {
                bf16x8 v = *reinterpret_cast<const bf16x8*>(Wob + (size_t)(e0 + it * 64 + r) * 128 + ko + c);
                *reinterpret_cast<bf16x8*>(&Bs[it * 64 + r][c]) = v;
            }
        }
        __syncthreads();
        #pragma unroll
        for (int kk = 0; kk < 2; ++kk) {
            bf16x8 af[2], bfr[4];
            #pragma unroll
            for (int mi = 0; mi < 2; ++mi)
                af[mi] = *reinterpret_cast<const bf16x8*>(&As[wm * 32 + mi * 16 + l15][kk * 32 + lg * 8]);
            #pragma unroll
            for (int ni = 0; ni < 4; ++ni)
                bfr[ni] = *reinterpret_cast<const bf16x8*>(&Bs[wn * 64 + ni * 16 + l15][kk * 32 + lg * 8]);
            #pragma unroll
            for (int mi = 0; mi < 2; ++mi)
                #pragma unroll
                for (int ni = 0; ni < 4; ++ni)
                    acc[mi][ni] = __builtin_amdgcn_mfma_f32_16x16x32_bf16(af[mi], bfr[ni], acc[mi][ni], 0, 0, 0);
        }
        __syncthreads();
    }
    #pragma unroll
    for (int mi = 0; mi < 2; ++mi) {
        #pragma unroll
        for (int i = 0; i < 4; ++i) {
            int m = row0 + wm * 32 + mi * 16 + lg * 4 + i;
            #pragma unroll
            for (int ni = 0; ni < 4; ++ni) {
                int e = e0 + wn * 64 + ni * 16 + l15;
                out[(size_t)m * 1024 + e] = acc[mi][ni][i] + bo[e];
            }
        }
    }
}

extern "C" void kernel_launch(void* const* d_in, const int* in_sizes, int n_in,
                              void* d_out, int out_size, void* d_ws, size_t ws_size,
                              hipStream_t stream)
{
    const float* patches     = (const float*)d_in[0];   // [256][196][1024]
    const float* queries     = (const float*)d_in[1];   // [52][128]
    const float* Wk          = (const float*)d_in[2];   // [128][1024]
    const float* Wv          = (const float*)d_in[3];   // [128][1024]
    const float* Wo          = (const float*)d_in[4];   // [1024][128]
    const float* bo          = (const float*)d_in[5];   // [1024]
    const float* patch_pos   = (const float*)d_in[6];   // [196][128]
    const float* temperature = (const float*)d_in[7];   // [1]
    const float* prior       = (const float*)d_in[8];   // [52][196]

    float* out      = (float*)d_out;                    // [256*52][1024]
    float* attn_out = out + (size_t)256 * 52 * 1024;    // [256*52][196]

    unsigned short* Wob = (unsigned short*)d_ws;               // 1024*128
    unsigned short* kv  = Wob + 1024 * 128;                    // 50176*256
    unsigned short* att = kv + (size_t)50176 * 256;            // 13312*128

    k_convert <<<128, 256, 0, stream>>>(Wo, Wob);
    k_keysvals<<<392, 512, 0, stream>>>(patches, Wk, Wv, patch_pos, kv);
    k_attn    <<<256, 1024, 0, stream>>>(kv, queries, prior, temperature, attn_out, att);
    k_out     <<<dim3(208, 4), 512, 0, stream>>>(att, Wob, bo, out);
}

// Round 9
// 178.600 us; speedup vs baseline: 2.0161x; 1.1036x over previous
//
#include <hip/hip_runtime.h>

typedef __attribute__((ext_vector_type(8))) short bf16x8;
typedef __attribute__((ext_vector_type(4))) short bf16x4;
typedef __attribute__((ext_vector_type(4))) float f32x4;
typedef __attribute__((ext_vector_type(4))) float floatx4;

__device__ __forceinline__ unsigned short f2bf(float f) {
    unsigned int u = __float_as_uint(f);
    u += 0x7fffu + ((u >> 16) & 1u);   // round-to-nearest-even
    return (unsigned short)(u >> 16);
}
__device__ __forceinline__ float bf2f_s(short h) {
    return __uint_as_float(((unsigned int)(unsigned short)h) << 16);
}

// pack 8 f32 -> bf16x8 via HW packed convert (RNE)
__device__ __forceinline__ bf16x8 cvt8(f32x4 lo, f32x4 hi) {
    union { unsigned int u[4]; bf16x8 v; } r;
    asm("v_cvt_pk_bf16_f32 %0, %1, %2" : "=v"(r.u[0]) : "v"(lo[0]), "v"(lo[1]));
    asm("v_cvt_pk_bf16_f32 %0, %1, %2" : "=v"(r.u[1]) : "v"(lo[2]), "v"(lo[3]));
    asm("v_cvt_pk_bf16_f32 %0, %1, %2" : "=v"(r.u[2]) : "v"(hi[0]), "v"(hi[1]));
    asm("v_cvt_pk_bf16_f32 %0, %1, %2" : "=v"(r.u[3]) : "v"(hi[2]), "v"(hi[3]));
    return r.v;
}

// ---------------- kernel 0: Wo -> bf16 ----------------
__global__ void k_convert(const float* __restrict__ Wo, unsigned short* __restrict__ Wob) {
    int i = (blockIdx.x * blockDim.x + threadIdx.x) * 4;
    if (i < 131072) {
        floatx4 c = *reinterpret_cast<const floatx4*>(Wo + i);
        bf16x4 sc;
        #pragma unroll
        for (int e = 0; e < 4; ++e) sc[e] = (short)f2bf(c[e]);
        *reinterpret_cast<bf16x4*>(Wob + i) = sc;
    }
}

// ---------------- kernel 1: keys/vals GEMM (4-set deep reg pipeline) ----------------
// kv[m][n] = sum_e patches[m][e] * bf16(W[n][e])  (+ patch_pos for n<128)
// BM=128 (grid 392), BN=256 (full N), BK=32. 512 thr, 8 waves (2M x 4N), wave 64x64.
// FOUR named register sets: tile t+4's global loads issued at step t, converted and
// ds_written at step t+3 (~3 steps of flight time) -> load latency fully hidden.
// Barrier flushes lgkmcnt only; vmcnt is never drained (compiler-counted waits).
__global__ __launch_bounds__(512, 2)
void k_keysvals(const float* __restrict__ patches,
                const float* __restrict__ Wk,
                const float* __restrict__ Wv,
                const float* __restrict__ patch_pos,
                unsigned short* __restrict__ kv)
{
    // per buffer: A 128 rows x 64B (8192B) | B 256 rows x 64B (16384B); row = 32 bf16.
    // Granule XOR swizzle g^(row&3) on BOTH write and read: <=2-way conflicts (free).
    __shared__ char ldsb[2][24576];

    const int tid  = threadIdx.x;
    const int lane = tid & 63;
    const int wave = tid >> 6;       // 0..7
    const int wm   = wave >> 2;      // 0..1 : 64-row half
    const int wn   = wave & 3;       // 0..3 : 64-col quarter
    const int l15  = lane & 15;
    const int lg   = lane >> 4;      // 0..3
    const int row0 = blockIdx.x * 128;

    // A staging: 4 threads/row; thread covers 32B (granules 2a4,2a4+1 of the f32 row)
    const int arow = tid >> 2;               // 0..127
    const int a4   = tid & 3;
    const float* agp = patches + (size_t)(row0 + arow) * 1024 + a4 * 8;

    // B staging: 2 threads/row; thread covers 64B (f32); waves 0-3 -> Wk, 4-7 -> Wv
    const int brow = tid >> 1;               // 0..255
    const int bh   = tid & 1;
    const float* bgp = ((wave < 4) ? (Wk + (size_t)brow * 1024)
                                   : (Wv + (size_t)(brow - 128) * 1024)) + bh * 16;

    // precomputed swizzled LDS byte offsets
    const int aoff = arow * 64 + (a4 ^ (arow & 3)) * 16;                 // A write
    const int boff1 = 8192 + brow * 64 + ((2 * bh)     ^ (brow & 3)) * 16;  // B write lo
    const int boff2 = 8192 + brow * 64 + ((2 * bh + 1) ^ (brow & 3)) * 16;  // B write hi
    const int ga   = lg ^ (l15 & 3);                                     // read granule

    struct Sset { f32x4 a0, a1, b0, b1, b2, b3; };
    Sset S0, S1, S2, S3;

    f32x4 acc[4][4];
    #pragma unroll
    for (int i = 0; i < 4; ++i)
        #pragma unroll
        for (int j = 0; j < 4; ++j)
            acc[i][j] = (f32x4){0.f, 0.f, 0.f, 0.f};

    auto issue = [&](Sset& s, int t) {
        const int ko = t * 32;
        s.a0 = *reinterpret_cast<const f32x4*>(agp + ko);
        s.a1 = *reinterpret_cast<const f32x4*>(agp + ko + 4);
        s.b0 = *reinterpret_cast<const f32x4*>(bgp + ko);
        s.b1 = *reinterpret_cast<const f32x4*>(bgp + ko + 4);
        s.b2 = *reinterpret_cast<const f32x4*>(bgp + ko + 8);
        s.b3 = *reinterpret_cast<const f32x4*>(bgp + ko + 12);
    };
    auto store = [&](const Sset& s, char* buf) {
        *reinterpret_cast<bf16x8*>(buf + aoff)  = cvt8(s.a0, s.a1);
        *reinterpret_cast<bf16x8*>(buf + boff1) = cvt8(s.b0, s.b1);
        *reinterpret_cast<bf16x8*>(buf + boff2) = cvt8(s.b2, s.b3);
    };
    auto compute = [&](const char* buf) {
        bf16x8 af[4], bf[4];
        #pragma unroll
        for (int mf = 0; mf < 4; ++mf) {
            const int r = wm * 64 + mf * 16 + l15;
            af[mf] = *reinterpret_cast<const bf16x8*>(buf + r * 64 + ga * 16);
        }
        #pragma unroll
        for (int nf = 0; nf < 4; ++nf) {
            const int r = wn * 64 + nf * 16 + l15;
            bf[nf] = *reinterpret_cast<const bf16x8*>(buf + 8192 + r * 64 + ga * 16);
        }
        #pragma unroll
        for (int mf = 0; mf < 4; ++mf)
            #pragma unroll
            for (int nf = 0; nf < 4; ++nf)
                acc[mf][nf] = __builtin_amdgcn_mfma_f32_16x16x32_bf16(af[mf], bf[nf], acc[mf][nf], 0, 0, 0);
    };

    // ---- prologue: fill all 4 sets, stage tile 0 ----
    issue(S0, 0); issue(S1, 1); issue(S2, 2); issue(S3, 3);
    store(S0, ldsb[0]);
    __builtin_amdgcn_sched_barrier(0);
    asm volatile("s_waitcnt lgkmcnt(0)" ::: "memory");
    __builtin_amdgcn_s_barrier();
    __builtin_amdgcn_sched_barrier(0);

    // KSTEP(T): issue(T+4) -> compute(T) -> store(T+1) -> fence
#define KSTEP(T, SST, SIS)                                              \
    do {                                                                \
        if ((T) + 4 < 32) issue(SIS, (T) + 4);                          \
        compute(ldsb[(T) & 1]);                                         \
        if ((T) + 1 < 32) {                                             \
            store(SST, ldsb[((T) + 1) & 1]);                            \
            __builtin_amdgcn_sched_barrier(0);                          \
            asm volatile("s_waitcnt lgkmcnt(0)" ::: "memory");          \
            __builtin_amdgcn_s_barrier();                               \
            __builtin_amdgcn_sched_barrier(0);                          \
        }                                                               \
    } while (0)

    for (int tb = 0; tb < 32; tb += 4) {
        KSTEP(tb + 0, S1, S0);
        KSTEP(tb + 1, S2, S1);
        KSTEP(tb + 2, S3, S2);
        KSTEP(tb + 3, S0, S3);
    }
#undef KSTEP

    // epilogue: C/D layout col=lane&15 (n), row=(lane>>4)*4+i (m)
    #pragma unroll
    for (int mf = 0; mf < 4; ++mf) {
        #pragma unroll
        for (int i = 0; i < 4; ++i) {
            int m  = row0 + wm * 64 + mf * 16 + lg * 4 + i;
            int kp = m % 196;
            #pragma unroll
            for (int nf = 0; nf < 4; ++nf) {
                int n = wn * 64 + nf * 16 + l15;
                float v = acc[mf][nf][i];
                if (wn < 2) v += patch_pos[kp * 128 + n];    // n<128 <=> wn<2
                kv[(size_t)m * 256 + n] = f2bf(v);
            }
        }
    }
}

// ---------------- kernel 2: per-batch attention ----------------
__global__ __launch_bounds__(1024)
void k_attn(const unsigned short* __restrict__ kv,
            const float* __restrict__ queries,
            const float* __restrict__ prior,
            const float* __restrict__ temperature,
            float* __restrict__ attn_out,
            unsigned short* __restrict__ att)
{
    __shared__ unsigned short k_s[196][136];
    __shared__ unsigned short v_s[196][128];
    __shared__ unsigned short q_s[52][128];
    __shared__ float          l_s[52][196];

    const int b   = blockIdx.x;
    const int tid = threadIdx.x;
    const size_t base = (size_t)b * 196 * 256;

    for (int idx = tid; idx < 6272; idx += 1024) {
        int row = idx >> 5;
        int c   = (idx & 31) * 8;
        bf16x8 v = *reinterpret_cast<const bf16x8*>(kv + base + row * 256 + c);
        if (c < 128) *reinterpret_cast<bf16x8*>(&k_s[row][c])       = v;
        else         *reinterpret_cast<bf16x8*>(&v_s[row][c - 128]) = v;
    }
    for (int idx = tid; idx < 1664; idx += 1024) {
        int row = idx >> 5;
        int c   = (idx & 31) * 4;
        const float* qp = queries + row * 128 + c;
        bf16x4 sv;
        sv[0] = (short)f2bf(qp[0]); sv[1] = (short)f2bf(qp[1]);
        sv[2] = (short)f2bf(qp[2]); sv[3] = (short)f2bf(qp[3]);
        *reinterpret_cast<bf16x4*>(&q_s[row][c]) = sv;
    }
    __syncthreads();

    const float inv_temp  = 1.0f / (log1pf(expf(temperature[0])) + 0.5f);
    const float inv_scale = 0.08838834764831845f;

    for (int task = tid; task < 3328; task += 1024) {
        int q  = task >> 6;
        int kg = task & 63;
        if (kg < 49) {
            float dot0 = 0.f, dot1 = 0.f, dot2 = 0.f, dot3 = 0.f;
            #pragma unroll 4
            for (int c = 0; c < 128; c += 8) {
                bf16x8 qv = *reinterpret_cast<const bf16x8*>(&q_s[q][c]);
                float qf[8];
                #pragma unroll
                for (int e = 0; e < 8; ++e) qf[e] = bf2f_s(qv[e]);
                bf16x8 k0v = *reinterpret_cast<const bf16x8*>(&k_s[kg][c]);
                bf16x8 k1v = *reinterpret_cast<const bf16x8*>(&k_s[kg + 49][c]);
                bf16x8 k2v = *reinterpret_cast<const bf16x8*>(&k_s[kg + 98][c]);
                bf16x8 k3v = *reinterpret_cast<const bf16x8*>(&k_s[kg + 147][c]);
                #pragma unroll
                for (int e = 0; e < 8; ++e) {
                    dot0 += qf[e] * bf2f_s(k0v[e]);
                    dot1 += qf[e] * bf2f_s(k1v[e]);
                    dot2 += qf[e] * bf2f_s(k2v[e]);
                    dot3 += qf[e] * bf2f_s(k3v[e]);
                }
            }
            int k;
            k = kg;       l_s[q][k] = (dot0 * inv_scale + prior[q * 196 + k]) * inv_temp;
            k = kg + 49;  l_s[q][k] = (dot1 * inv_scale + prior[q * 196 + k]) * inv_temp;
            k = kg + 98;  l_s[q][k] = (dot2 * inv_scale + prior[q * 196 + k]) * inv_temp;
            k = kg + 147; l_s[q][k] = (dot3 * inv_scale + prior[q * 196 + k]) * inv_temp;
        }
    }
    __syncthreads();

    const int lane = tid & 63;
    const int wave = tid >> 6;
    for (int q = wave; q < 52; q += 16) {
        float x0 = l_s[q][lane];
        float x1 = l_s[q][lane + 64];
        float x2 = l_s[q][lane + 128];
        float x3 = (lane < 4) ? l_s[q][lane + 192] : -1e30f;
        float m = fmaxf(fmaxf(x0, x1), fmaxf(x2, x3));
        #pragma unroll
        for (int off = 32; off > 0; off >>= 1) m = fmaxf(m, __shfl_xor(m, off));
        float e0 = expf(x0 - m), e1 = expf(x1 - m), e2 = expf(x2 - m);
        float e3 = (lane < 4) ? expf(x3 - m) : 0.0f;
        float s = e0 + e1 + e2 + e3;
        #pragma unroll
        for (int off = 32; off > 0; off >>= 1) s += __shfl_xor(s, off);
        float inv = 1.0f / s;
        float* po = attn_out + ((size_t)b * 52 + q) * 196;
        float a0 = e0 * inv, a1 = e1 * inv, a2 = e2 * inv;
        l_s[q][lane]       = a0;  po[lane]       = a0;
        l_s[q][lane + 64]  = a1;  po[lane + 64]  = a1;
        l_s[q][lane + 128] = a2;  po[lane + 128] = a2;
        if (lane < 4) { float a3 = e3 * inv; l_s[q][lane + 192] = a3; po[lane + 192] = a3; }
    }
    __syncthreads();

    if (tid < 832) {
        int q  = tid >> 4;
        int a0 = (tid & 15) * 8;
        float accv[8] = {0.f, 0.f, 0.f, 0.f, 0.f, 0.f, 0.f, 0.f};
        for (int k = 0; k < 196; ++k) {
            float w = l_s[q][k];
            bf16x8 vv = *reinterpret_cast<const bf16x8*>(&v_s[k][a0]);
            #pragma unroll
            for (int e = 0; e < 8; ++e) accv[e] += w * bf2f_s(vv[e]);
        }
        bf16x8 sv;
        #pragma unroll
        for (int e = 0; e < 8; ++e) sv[e] = (short)f2bf(accv[e]);
        *reinterpret_cast<bf16x8*>(att + ((size_t)b * 52 + q) * 128 + a0) = sv;
    }
}

// ---------------- kernel 3: output GEMM ----------------
__global__ __launch_bounds__(512)
void k_out(const unsigned short* __restrict__ att,
           const unsigned short* __restrict__ Wob,
           const float* __restrict__ bo,
           float* __restrict__ out)
{
    __shared__ unsigned short As[64][72];
    __shared__ unsigned short Bs[256][72];

    const int tid  = threadIdx.x;
    const int lane = tid & 63;
    const int wave = tid >> 6;
    const int wm   = wave >> 2;
    const int wn   = wave & 3;
    const int l15  = lane & 15;
    const int lg   = lane >> 4;
    const int row0 = blockIdx.x * 64;
    const int e0   = blockIdx.y * 256;

    f32x4 acc[2][4];
    #pragma unroll
    for (int i = 0; i < 2; ++i)
        #pragma unroll
        for (int j = 0; j < 4; ++j)
            acc[i][j] = (f32x4){0.f, 0.f, 0.f, 0.f};

    for (int ko = 0; ko < 128; ko += 64) {
        {
            int r = tid >> 3;
            int c = (tid & 7) * 8;
            bf16x8 v = *reinterpret_cast<const bf16x8*>(att + (size_t)(row0 + r) * 128 + ko + c);
            *reinterpret_cast<bf16x8*>(&As[r][c]) = v;
        }
        {
            int r = tid >> 3;
            int c = (tid & 7) * 8;
            #pragma unroll
            for (int it = 0; it < 4; ++it) {
                bf16x8 v = *reinterpret_cast<const bf16x8*>(Wob + (size_t)(e0 + it * 64 + r) * 128 + ko + c);
                *reinterpret_cast<bf16x8*>(&Bs[it * 64 + r][c]) = v;
            }
        }
        __syncthreads();
        #pragma unroll
        for (int kk = 0; kk < 2; ++kk) {
            bf16x8 af[2], bfr[4];
            #pragma unroll
            for (int mi = 0; mi < 2; ++mi)
                af[mi] = *reinterpret_cast<const bf16x8*>(&As[wm * 32 + mi * 16 + l15][kk * 32 + lg * 8]);
            #pragma unroll
            for (int ni = 0; ni < 4; ++ni)
                bfr[ni] = *reinterpret_cast<const bf16x8*>(&Bs[wn * 64 + ni * 16 + l15][kk * 32 + lg * 8]);
            #pragma unroll
            for (int mi = 0; mi < 2; ++mi)
                #pragma unroll
                for (int ni = 0; ni < 4; ++ni)
                    acc[mi][ni] = __builtin_amdgcn_mfma_f32_16x16x32_bf16(af[mi], bfr[ni], acc[mi][ni], 0, 0, 0);
        }
        __syncthreads();
    }
    #pragma unroll
    for (int mi = 0; mi < 2; ++mi) {
        #pragma unroll
        for (int i = 0; i < 4; ++i) {
            int m = row0 + wm * 32 + mi * 16 + lg * 4 + i;
            #pragma unroll
            for (int ni = 0; ni < 4; ++ni) {
                int e = e0 + wn * 64 + ni * 16 + l15;
                out[(size_t)m * 1024 + e] = acc[mi][ni][i] + bo[e];
            }
        }
    }
}

extern "C" void kernel_launch(void* const* d_in, const int* in_sizes, int n_in,
                              void* d_out, int out_size, void* d_ws, size_t ws_size,
                              hipStream_t stream)
{
    const float* patches     = (const float*)d_in[0];   // [256][196][1024]
    const float* queries     = (const float*)d_in[1];   // [52][128]
    const float* Wk          = (const float*)d_in[2];   // [128][1024]
    const float* Wv          = (const float*)d_in[3];   // [128][1024]
    const float* Wo          = (const float*)d_in[4];   // [1024][128]
    const float* bo          = (const float*)d_in[5];   // [1024]
    const float* patch_pos   = (const float*)d_in[6];   // [196][128]
    const float* temperature = (const float*)d_in[7];   // [1]
    const float* prior       = (const float*)d_in[8];   // [52][196]

    float* out      = (float*)d_out;                    // [256*52][1024]
    float* attn_out = out + (size_t)256 * 52 * 1024;    // [256*52][196]

    unsigned short* Wob = (unsigned short*)d_ws;               // 1024*128
    unsigned short* kv  = Wob + 1024 * 128;                    // 50176*256
    unsigned short* att = kv + (size_t)50176 * 256;            // 13312*128

    k_convert <<<128, 256, 0, stream>>>(Wo, Wob);
    k_keysvals<<<392, 512, 0, stream>>>(patches, Wk, Wv, patch_pos, kv);
    k_attn    <<<256, 1024, 0, stream>>>(kv, queries, prior, temperature, attn_out, att);
    k_out     <<<dim3(208, 4), 512, 0, stream>>>(att, Wob, bo, out);
}